// Round 11
// baseline (1582.311 us; speedup 1.0000x reference)
//
#include <hip/hip_runtime.h>
#include <math.h>

#define NROWS 8192
#define DIM   64
#define KSEL  32
#define NQ    (NROWS - KSEL)   /* 8160 query rows */
#define QPB   64               /* queries per wave */
#define NQB   128              /* NQ/QPB rounded up */
#define CHUNK 256              /* pass-2 candidate chunk */
#define MAXC  (NROWS / CHUNK)  /* 32 partial slots per query */
#define P1LEN 512              /* pass-1 prefix (chunks 0 and 1) */

// ---------------------------------------------------------------------------
// Kernel A: row norms replicating XLA:CPU (LLVM-vectorized fused reduce):
//   VF=8 lanes, init 0, per-lane FMA chain, horizontal shuffle-tree
//   ((r0+r4)+(r2+r6)) + ((r1+r5)+(r3+r7)).   [validated bit-exact R8-R10]
// ---------------------------------------------------------------------------
__global__ void norms_kernel(const float* __restrict__ x, float* __restrict__ sq) {
    int j = blockIdx.x * blockDim.x + threadIdx.x;
    if (j >= NROWS) return;
    const float* xr = x + (size_t)j * DIM;
    float r[8];
#pragma unroll
    for (int u = 0; u < 8; ++u) r[u] = 0.0f;
#pragma unroll
    for (int i = 0; i < DIM; i += 8) {
#pragma unroll
        for (int u = 0; u < 8; ++u)
            r[u] = __fmaf_rn(xr[i + u], xr[i + u], r[u]);
    }
    const float s04 = __fadd_rn(r[0], r[4]);
    const float s26 = __fadd_rn(r[2], r[6]);
    const float s15 = __fadd_rn(r[1], r[5]);
    const float s37 = __fadd_rn(r[3], r[7]);
    sq[j] = __fadd_rn(__fadd_rn(s04, s26), __fadd_rn(s15, s37));
}

// ---------------------------------------------------------------------------
// Per-lane 32-entry max-heap of u64 keys in LDS (stride 33).
// Keeps the 32 SMALLEST keys; root (tau) = largest kept.  Precondition k < tau.
// ---------------------------------------------------------------------------
__device__ inline void heap_insert(unsigned long long* H, unsigned long long k,
                                   unsigned long long& tau) {
    unsigned i = 0;
    while (true) {
        const unsigned l = 2 * i + 1;
        if (l >= KSEL) break;
        const unsigned rr = l + 1;
        unsigned long long cb = H[l];
        unsigned bi = l;
        if (rr < KSEL) {
            const unsigned long long cr = H[rr];
            if (cr > cb) { cb = cr; bi = rr; }
        }
        if (cb > k) {
            H[i] = cb;
            if (i == 0) tau = cb;
            i = bi;
        } else break;
    }
    H[i] = k;
    if (i == 0) tau = k;
}

// Shared distance body: 4 candidates per step, bit-exact sequential FMA chain
// (Eigen gebp order), dist = fl(fl(sqr+sqj) - fl(2*dot)) clamped at 0.
#define DIST4_AND_INSERT(j0)                                                     \
    {                                                                            \
        const float* c0 = x + (size_t)(j0) * DIM;                                \
        float a0 = 0.0f, a1 = 0.0f, a2 = 0.0f, a3 = 0.0f;                        \
        _Pragma("unroll")                                                        \
        for (int d = 0; d < DIM; ++d) {                                          \
            const float qd = q[d];                                               \
            a0 = __fmaf_rn(qd, c0[d], a0);                                       \
            a1 = __fmaf_rn(qd, c0[d + DIM], a1);                                 \
            a2 = __fmaf_rn(qd, c0[d + 2 * DIM], a2);                             \
            a3 = __fmaf_rn(qd, c0[d + 3 * DIM], a3);                             \
        }                                                                        \
        const float s0 = sq[(j0)], s1 = sq[(j0) + 1];                            \
        const float s2 = sq[(j0) + 2], s3 = sq[(j0) + 3];                        \
        const float d0 = fmaxf(__fsub_rn(__fadd_rn(sqr, s0), __fmul_rn(2.0f, a0)), 0.0f); \
        const float d1 = fmaxf(__fsub_rn(__fadd_rn(sqr, s1), __fmul_rn(2.0f, a1)), 0.0f); \
        const float d2 = fmaxf(__fsub_rn(__fadd_rn(sqr, s2), __fmul_rn(2.0f, a2)), 0.0f); \
        const float d3 = fmaxf(__fsub_rn(__fadd_rn(sqr, s3), __fmul_rn(2.0f, a3)), 0.0f); \
        const unsigned long long k0 =                                            \
            ((unsigned long long)__float_as_uint(d0) << 32) | (unsigned)(j0);    \
        const unsigned long long k1 =                                            \
            ((unsigned long long)__float_as_uint(d1) << 32) | (unsigned)((j0) + 1); \
        const unsigned long long k2 =                                            \
            ((unsigned long long)__float_as_uint(d2) << 32) | (unsigned)((j0) + 2); \
        const unsigned long long k3 =                                            \
            ((unsigned long long)__float_as_uint(d3) << 32) | (unsigned)((j0) + 3); \
        if ((j0) < r && k0 < tau)     heap_insert(H, k0, tau);                   \
        if ((j0) + 1 < r && k1 < tau) heap_insert(H, k1, tau);                   \
        if ((j0) + 2 < r && k2 < tau) heap_insert(H, k2, tau);                   \
        if ((j0) + 3 < r && k3 < tau) heap_insert(H, k3, tau);                   \
    }

// ---------------------------------------------------------------------------
// Pass 1: exact top-32 over prefix [0, min(P1LEN, r)).  Writes partial slot 0,
// clears slot 1 (prefix covers chunks 0-1), publishes tau0 = root key (the
// 32nd-smallest of the prefix -- a SAFE upper bound on the true 32nd).
// ---------------------------------------------------------------------------
__global__ __launch_bounds__(QPB)
void pass1_kernel(const float* __restrict__ x, const float* __restrict__ sq,
                  unsigned long long* __restrict__ partial,
                  unsigned long long* __restrict__ tau0) {
    const int qb   = blockIdx.x;
    const int lane = threadIdx.x;
    const int  r_raw = KSEL + qb * QPB + lane;
    const bool vq    = (r_raw < NROWS);
    const int  r     = vq ? r_raw : 0;
    const int  qrow  = vq ? r_raw : 0;

    __shared__ unsigned long long heap[QPB * 33];
    unsigned long long* H = heap + lane * 33;
#pragma unroll
    for (int s = 0; s < KSEL; ++s) H[s] = ~0ull;
    unsigned long long tau = ~0ull;

    float q[DIM];
    const float4* q4 = reinterpret_cast<const float4*>(x + (size_t)qrow * DIM);
#pragma unroll
    for (int i = 0; i < DIM / 4; ++i) {
        float4 v = q4[i];
        q[4 * i + 0] = v.x; q[4 * i + 1] = v.y;
        q[4 * i + 2] = v.z; q[4 * i + 3] = v.w;
    }
    const float sqr = sq[qrow];

    for (int j0 = 0; j0 < P1LEN; j0 += 4) DIST4_AND_INSERT(j0);

    if (vq) {
        const int qi = r_raw - KSEL;
        unsigned long long* dst0 = partial + ((size_t)qi * MAXC + 0) * KSEL;
        unsigned long long* dst1 = partial + ((size_t)qi * MAXC + 1) * KSEL;
#pragma unroll
        for (int s = 0; s < KSEL; ++s) { dst0[s] = H[s]; dst1[s] = ~0ull; }
        tau0[qi] = H[0];
    }
}

// ---------------------------------------------------------------------------
// Pass 2: chunks c = 2..31.  Block = 2 independent waves (33.8 KB LDS ->
// 4 blocks/CU = 8 waves/CU resident).  Heap pre-filled with 32 copies of the
// pass-1 root key (tau0): only candidates beating the safe bound are inserted
// (~32/512 acceptance).  Duplicate sentinel keys are scrubbed by the merge.
// ---------------------------------------------------------------------------
__global__ __launch_bounds__(128)
void pass2_kernel(const float* __restrict__ x, const float* __restrict__ sq,
                  const unsigned long long* __restrict__ tau0,
                  unsigned long long* __restrict__ partial) {
    const int qb   = blockIdx.x;
    const int wave = threadIdx.x >> 6;
    const int lane = threadIdx.x & 63;
    const int c    = 2 + blockIdx.y * 2 + wave;          // 2..31

    const int r_hi = min(KSEL + (qb + 1) * QPB, NROWS);
    const int jbeg = c * CHUNK;
    if (jbeg >= r_hi) return;                            // no barriers: safe
    const int jend = min(jbeg + CHUNK, r_hi);            // multiples of 4

    const int  r_raw = KSEL + qb * QPB + lane;
    const bool vq    = (r_raw < NROWS);
    const int  r     = vq ? r_raw : 0;
    const int  qrow  = vq ? r_raw : 0;
    const int  qi    = vq ? (r_raw - KSEL) : 0;

    __shared__ unsigned long long heap[128 * 33];        // 33792 B
    unsigned long long* H = heap + threadIdx.x * 33;
    const unsigned long long t0 = vq ? tau0[qi] : 0ull;  // 0 => reject all
#pragma unroll
    for (int s = 0; s < KSEL; ++s) H[s] = t0;
    unsigned long long tau = t0;

    float q[DIM];
    const float4* q4 = reinterpret_cast<const float4*>(x + (size_t)qrow * DIM);
#pragma unroll
    for (int i = 0; i < DIM / 4; ++i) {
        float4 v = q4[i];
        q[4 * i + 0] = v.x; q[4 * i + 1] = v.y;
        q[4 * i + 2] = v.z; q[4 * i + 3] = v.w;
    }
    const float sqr = sq[qrow];

    for (int j0 = jbeg; j0 < jend; j0 += 4) DIST4_AND_INSERT(j0);

    if (vq && jbeg < r) {     // merge reads slot c only when c < ceil(r/CHUNK)
        unsigned long long* dst = partial + ((size_t)qi * MAXC + c) * KSEL;
#pragma unroll
        for (int s = 0; s < KSEL; ++s) dst[s] = H[s];
    }
}

// ---------------------------------------------------------------------------
// Kernel C: merge partials -> exact global top-32 per query.  256 threads,
// up to 1024 entries.  u64-min = ascending (dist, index), low-index ties.
// Scrubs ALL copies of the extracted key (dedupes tau0 sentinels).
// ---------------------------------------------------------------------------
__global__ __launch_bounds__(256)
void merge_kernel(const unsigned long long* __restrict__ partial,
                  float* __restrict__ out_d, float* __restrict__ out_i) {
    const int qi  = blockIdx.x;     // 0..8159
    const int rr  = qi + KSEL;
    const int tid = threadIdx.x;
    const int nc  = (rr + CHUNK - 1) / CHUNK;
    const int ne  = nc * KSEL;      // <= 1024

    __shared__ unsigned long long red[4];

    const unsigned long long* src = partial + (size_t)qi * MAXC * KSEL;
    unsigned long long e[4];
#pragma unroll
    for (int s = 0; s < 4; ++s) {
        const int idx = s * 256 + tid;
        e[s] = (idx < ne) ? src[idx] : ~0ull;
    }
    unsigned long long pmin = ~0ull;
#pragma unroll
    for (int s = 0; s < 4; ++s) pmin = e[s] < pmin ? e[s] : pmin;

    for (int it = 0; it < KSEL; ++it) {
        unsigned long long v = pmin;
#pragma unroll
        for (int off = 32; off > 0; off >>= 1) {
            const unsigned long long o = __shfl_down(v, off, 64);
            v = o < v ? o : v;
        }
        if ((tid & 63) == 0) red[tid >> 6] = v;
        __syncthreads();
        unsigned long long g = red[0];
#pragma unroll
        for (int w = 1; w < 4; ++w) g = red[w] < g ? red[w] : g;

        if (tid == 0) {
            out_d[(size_t)qi * KSEL + it] = __uint_as_float((unsigned)(g >> 32));
            out_i[(size_t)qi * KSEL + it] = (float)(unsigned)(g & 0xFFFFFFFFu);
        }
        if (pmin == g) {   // scrub every copy of g (keys may be duplicated)
#pragma unroll
            for (int s = 0; s < 4; ++s) if (e[s] == g) e[s] = ~0ull;
            pmin = ~0ull;
#pragma unroll
            for (int s = 0; s < 4; ++s) pmin = e[s] < pmin ? e[s] : pmin;
        }
        __syncthreads();   // red[] reuse
    }
}

extern "C" void kernel_launch(void* const* d_in, const int* in_sizes, int n_in,
                              void* d_out, int out_size, void* d_ws, size_t ws_size,
                              hipStream_t stream) {
    const float* x = (const float*)d_in[0];    // anchor_x [8192, 64] fp32
    float* sq = (float*)d_ws;                                       // 32 KB
    unsigned long long* tau0 =
        (unsigned long long*)((char*)d_ws + 32768);                 // 64 KB
    unsigned long long* partial =
        (unsigned long long*)((char*)d_ws + 32768 + 65536);         // 66.8 MB
    float* out_d = (float*)d_out;              // [8160, 32] distances
    float* out_i = out_d + (size_t)NQ * KSEL;  // [8160, 32] indices (as fp32)

    norms_kernel<<<NROWS / 256, 256, 0, stream>>>(x, sq);
    pass1_kernel<<<NQB, QPB, 0, stream>>>(x, sq, partial, tau0);
    dim3 g2(NQB, 15);                          // c = 2 + by*2 + wave -> 2..31
    pass2_kernel<<<g2, 128, 0, stream>>>(x, sq, tau0, partial);
    merge_kernel<<<NQ, 256, 0, stream>>>(partial, out_d, out_i);
}

// Round 12
// 655.444 us; speedup vs baseline: 2.4141x; 2.4141x over previous
//
#include <hip/hip_runtime.h>
#include <math.h>

#define NROWS 8192
#define DIM   64
#define KSEL  32
#define NQ    (NROWS - KSEL)   /* 8160 query rows */
#define QPB   64               /* queries per wave in pass2 */
#define NQB   128              /* NQ/QPB rounded up */
#define TILE  128              /* pass-2 candidate tile */
#define P1LEN 512              /* pass-1 prefix length */
#define CAP   1008             /* per-query candidate list capacity */

// ---------------------------------------------------------------------------
// Kernel A: row norms replicating XLA:CPU (LLVM-vectorized fused reduce):
//   VF=8 lanes, init 0, per-lane FMA chain, horizontal shuffle-tree
//   ((r0+r4)+(r2+r6)) + ((r1+r5)+(r3+r7)).   [validated bit-exact R8-R11]
// ---------------------------------------------------------------------------
__global__ void norms_kernel(const float* __restrict__ x, float* __restrict__ sq) {
    int j = blockIdx.x * blockDim.x + threadIdx.x;
    if (j >= NROWS) return;
    const float* xr = x + (size_t)j * DIM;
    float r[8];
#pragma unroll
    for (int u = 0; u < 8; ++u) r[u] = 0.0f;
#pragma unroll
    for (int i = 0; i < DIM; i += 8) {
#pragma unroll
        for (int u = 0; u < 8; ++u)
            r[u] = __fmaf_rn(xr[i + u], xr[i + u], r[u]);
    }
    const float s04 = __fadd_rn(r[0], r[4]);
    const float s26 = __fadd_rn(r[2], r[6]);
    const float s15 = __fadd_rn(r[1], r[5]);
    const float s37 = __fadd_rn(r[3], r[7]);
    sq[j] = __fadd_rn(__fadd_rn(s04, s26), __fadd_rn(s15, s37));
}

// ---------------------------------------------------------------------------
// Pass 1: tau0[qi] = EXACT 32nd-smallest key over prefix [0, min(512, r)).
// One block per query, 256 threads, 2 candidates/thread, distances in LDS,
// 32 extract-min iterations (validated R8 selection idiom).
// Safe bound: 32nd-of-subset >= 32nd-of-full-set.
// ---------------------------------------------------------------------------
__global__ __launch_bounds__(256)
void pass1_kernel(const float* __restrict__ x, const float* __restrict__ sq,
                  unsigned long long* __restrict__ tau0) {
    const int qi  = blockIdx.x;         // 0..8159
    const int r   = qi + KSEL;          // query row
    const int tid = threadIdx.x;
    const int P   = min(r, P1LEN);

    __shared__ unsigned long long keys[P1LEN];
    __shared__ unsigned long long red[4];
    __shared__ float qs[DIM];

    if (tid < DIM) qs[tid] = x[(size_t)r * DIM + tid];
    __syncthreads();

    float qv[DIM];
#pragma unroll
    for (int d = 0; d < DIM; ++d) qv[d] = qs[d];
    const float sqr = sq[r];

    // Bit-exact distance: sequential FMA chain k=0..63 (Eigen gebp order),
    // dist = fl(fl(sqr+sqj) - fl(2*dot)) clamped at 0.
#pragma unroll
    for (int c = 0; c < 2; ++c) {
        const int j = tid + c * 256;
        unsigned long long key = ~0ull;
        if (j < P) {
            const float4* cr4 = reinterpret_cast<const float4*>(x + (size_t)j * DIM);
            float acc = 0.0f;
#pragma unroll
            for (int i = 0; i < DIM / 4; ++i) {
                float4 v = cr4[i];
                acc = __fmaf_rn(qv[4 * i + 0], v.x, acc);
                acc = __fmaf_rn(qv[4 * i + 1], v.y, acc);
                acc = __fmaf_rn(qv[4 * i + 2], v.z, acc);
                acc = __fmaf_rn(qv[4 * i + 3], v.w, acc);
            }
            const float dd =
                fmaxf(__fsub_rn(__fadd_rn(sqr, sq[j]), __fmul_rn(2.0f, acc)), 0.0f);
            key = ((unsigned long long)__float_as_uint(dd) << 32) | (unsigned)j;
        }
        keys[j >= 0 ? (tid + c * 256) : 0] = key;
    }
    __syncthreads();

    unsigned long long k0 = keys[tid], k1 = keys[tid + 256];
    unsigned long long pmin = k0 < k1 ? k0 : k1;
    unsigned long long g = ~0ull;
    for (int it = 0; it < KSEL; ++it) {
        unsigned long long v = pmin;
#pragma unroll
        for (int off = 32; off > 0; off >>= 1) {
            const unsigned long long o = __shfl_down(v, off, 64);
            v = o < v ? o : v;
        }
        if ((tid & 63) == 0) red[tid >> 6] = v;
        __syncthreads();
        g = red[0];
#pragma unroll
        for (int w = 1; w < 4; ++w) g = red[w] < g ? red[w] : g;
        if (pmin == g) {   // unique winner (keys embed unique j)
            if (keys[tid] == g) keys[tid] = ~0ull;
            if (keys[tid + 256] == g) keys[tid + 256] = ~0ull;
            const unsigned long long a = keys[tid], b = keys[tid + 256];
            pmin = a < b ? a : b;
        }
        __syncthreads();   // red[] reuse
    }
    if (tid == 0) tau0[qi] = g;   // 32nd smallest key of the prefix
}

// ---------------------------------------------------------------------------
// Pass 2: full triangle filter.  Query-per-lane (broadcast candidate loads),
// NO LDS.  Accept key <= tau0 (superset of true top-32), append to per-query
// list via atomicAdd.  Grid (qb, tile); 1-wave blocks.
// ---------------------------------------------------------------------------
__global__ __launch_bounds__(64, 4)
void pass2_kernel(const float* __restrict__ x, const float* __restrict__ sq,
                  const unsigned long long* __restrict__ tau0,
                  unsigned int* __restrict__ cnt,
                  unsigned long long* __restrict__ lists) {
    const int qb   = blockIdx.x;
    const int t    = blockIdx.y;
    const int lane = threadIdx.x;

    const int r_hi = min(KSEL + (qb + 1) * QPB, NROWS);
    const int jbeg = t * TILE;
    if (jbeg >= r_hi) return;
    const int jend = min(jbeg + TILE, r_hi);    // multiple of 4 (r_hi%4==0)

    const int  r_raw = KSEL + qb * QPB + lane;
    const bool vq    = (r_raw < NROWS);
    const int  r     = vq ? r_raw : 0;          // r=0 => never accepts
    const int  qrow  = vq ? r_raw : 0;
    const int  qi    = vq ? (r_raw - KSEL) : 0;
    const unsigned long long tau = vq ? tau0[qi] : 0ull;

    float q[DIM];
    const float4* q4 = reinterpret_cast<const float4*>(x + (size_t)qrow * DIM);
#pragma unroll
    for (int i = 0; i < DIM / 4; ++i) {
        float4 v = q4[i];
        q[4 * i + 0] = v.x; q[4 * i + 1] = v.y;
        q[4 * i + 2] = v.z; q[4 * i + 3] = v.w;
    }
    const float sqr = sq[qrow];

    for (int j0 = jbeg; j0 < jend; j0 += 4) {
        const float* c0 = x + (size_t)j0 * DIM;
        float a0 = 0.0f, a1 = 0.0f, a2 = 0.0f, a3 = 0.0f;
#pragma unroll
        for (int d = 0; d < DIM; ++d) {         // bit-exact seq chains, ILP-4
            const float qd = q[d];
            a0 = __fmaf_rn(qd, c0[d], a0);
            a1 = __fmaf_rn(qd, c0[d + DIM], a1);
            a2 = __fmaf_rn(qd, c0[d + 2 * DIM], a2);
            a3 = __fmaf_rn(qd, c0[d + 3 * DIM], a3);
        }
        const float s0 = sq[j0], s1 = sq[j0 + 1], s2 = sq[j0 + 2], s3 = sq[j0 + 3];
        const float d0 = fmaxf(__fsub_rn(__fadd_rn(sqr, s0), __fmul_rn(2.0f, a0)), 0.0f);
        const float d1 = fmaxf(__fsub_rn(__fadd_rn(sqr, s1), __fmul_rn(2.0f, a1)), 0.0f);
        const float d2 = fmaxf(__fsub_rn(__fadd_rn(sqr, s2), __fmul_rn(2.0f, a2)), 0.0f);
        const float d3 = fmaxf(__fsub_rn(__fadd_rn(sqr, s3), __fmul_rn(2.0f, a3)), 0.0f);
        const unsigned long long k0 =
            ((unsigned long long)__float_as_uint(d0) << 32) | (unsigned)j0;
        const unsigned long long k1 =
            ((unsigned long long)__float_as_uint(d1) << 32) | (unsigned)(j0 + 1);
        const unsigned long long k2 =
            ((unsigned long long)__float_as_uint(d2) << 32) | (unsigned)(j0 + 2);
        const unsigned long long k3 =
            ((unsigned long long)__float_as_uint(d3) << 32) | (unsigned)(j0 + 3);
        if (j0 < r && k0 <= tau) {
            unsigned s = atomicAdd(&cnt[qi], 1u);
            if (s < CAP) lists[(size_t)qi * CAP + s] = k0;
        }
        if (j0 + 1 < r && k1 <= tau) {
            unsigned s = atomicAdd(&cnt[qi], 1u);
            if (s < CAP) lists[(size_t)qi * CAP + s] = k1;
        }
        if (j0 + 2 < r && k2 <= tau) {
            unsigned s = atomicAdd(&cnt[qi], 1u);
            if (s < CAP) lists[(size_t)qi * CAP + s] = k2;
        }
        if (j0 + 3 < r && k3 <= tau) {
            unsigned s = atomicAdd(&cnt[qi], 1u);
            if (s < CAP) lists[(size_t)qi * CAP + s] = k3;
        }
    }
}

// ---------------------------------------------------------------------------
// Merge: per-query top-32 over its candidate list (staged in LDS).
// u64-min = ascending (dist, index), low-index ties (validated semantics).
// ---------------------------------------------------------------------------
__global__ __launch_bounds__(256)
void merge_kernel(const unsigned long long* __restrict__ lists,
                  const unsigned int* __restrict__ cnt,
                  float* __restrict__ out_d, float* __restrict__ out_i) {
    const int qi  = blockIdx.x;     // 0..8159
    const int tid = threadIdx.x;

    __shared__ unsigned long long K[CAP];
    __shared__ unsigned long long red[4];

    const int ne = min((int)cnt[qi], CAP);
    const unsigned long long* src = lists + (size_t)qi * CAP;
#pragma unroll
    for (int s = 0; s < 4; ++s) {
        const int idx = s * 256 + tid;
        if (idx < CAP) K[idx] = (idx < ne) ? src[idx] : ~0ull;
    }
    __syncthreads();

    unsigned long long pmin = ~0ull;
#pragma unroll
    for (int s = 0; s < 4; ++s) {
        const int idx = s * 256 + tid;
        if (idx < CAP) { const unsigned long long k = K[idx]; pmin = k < pmin ? k : pmin; }
    }

    for (int it = 0; it < KSEL; ++it) {
        unsigned long long v = pmin;
#pragma unroll
        for (int off = 32; off > 0; off >>= 1) {
            const unsigned long long o = __shfl_down(v, off, 64);
            v = o < v ? o : v;
        }
        if ((tid & 63) == 0) red[tid >> 6] = v;
        __syncthreads();
        unsigned long long g = red[0];
#pragma unroll
        for (int w = 1; w < 4; ++w) g = red[w] < g ? red[w] : g;

        if (tid == 0) {
            out_d[(size_t)qi * KSEL + it] = __uint_as_float((unsigned)(g >> 32));
            out_i[(size_t)qi * KSEL + it] = (float)(unsigned)(g & 0xFFFFFFFFu);
        }
        if (pmin == g) {   // unique winner rescans its slots
            pmin = ~0ull;
#pragma unroll
            for (int s = 0; s < 4; ++s) {
                const int idx = s * 256 + tid;
                if (idx < CAP) {
                    if (K[idx] == g) K[idx] = ~0ull;
                    const unsigned long long k = K[idx];
                    pmin = k < pmin ? k : pmin;
                }
            }
        }
        __syncthreads();   // red[] reuse
    }
}

extern "C" void kernel_launch(void* const* d_in, const int* in_sizes, int n_in,
                              void* d_out, int out_size, void* d_ws, size_t ws_size,
                              hipStream_t stream) {
    const float* x = (const float*)d_in[0];    // anchor_x [8192, 64] fp32
    float* sq = (float*)d_ws;                                        // 32 KB
    unsigned long long* tau0 =
        (unsigned long long*)((char*)d_ws + 32768);                  // 64 KB
    unsigned int* cnt = (unsigned int*)((char*)d_ws + 98304);        // 32 KB
    unsigned long long* lists =
        (unsigned long long*)((char*)d_ws + 131072);                 // 65.8 MB
    float* out_d = (float*)d_out;              // [8160, 32] distances
    float* out_i = out_d + (size_t)NQ * KSEL;  // [8160, 32] indices (as fp32)

    norms_kernel<<<NROWS / 256, 256, 0, stream>>>(x, sq);
    pass1_kernel<<<NQ, 256, 0, stream>>>(x, sq, tau0);
    hipMemsetAsync(cnt, 0, NQ * sizeof(unsigned int), stream);
    dim3 g2(NQB, NROWS / TILE);
    pass2_kernel<<<g2, QPB, 0, stream>>>(x, sq, tau0, cnt, lists);
    merge_kernel<<<NQ, 256, 0, stream>>>(lists, cnt, out_d, out_i);
}